// Round 1
// baseline (149.274 us; speedup 1.0000x reference)
//
#include <hip/hip_runtime.h>
#include <cstdint>

#define BATCH 4
#define TQ 256
#define TK 256
#define DIM 256
#define HD 256

typedef _Float16 f16x8 __attribute__((ext_vector_type(8)));
typedef float f32x4 __attribute__((ext_vector_type(4)));

union U4H8 { uint4 u; f16x8 v; };

// Opaque def+use: forces the value to be materialized in a VGPR here and
// prevents the compiler from sinking/rematerializing the producing load.
#define KEEP(x) asm volatile("" : "+v"(x))

__device__ __forceinline__ unsigned short f2h(float f) {
    _Float16 h = (_Float16)f;
    unsigned short u;
    __builtin_memcpy(&u, &h, 2);
    return u;
}

__device__ __forceinline__ uint32_t pk2h(float a, float b) {
    auto r = __builtin_amdgcn_cvt_pkrtz(a, b);
    uint32_t w;
    __builtin_memcpy(&w, &r, 4);
    return w;
}

// Fused prep: blocks 0..511  -> qh = queries@W1[256:]+b1, kh = keys@W1[:256]
//             blocks 512..575 -> W2T[n][c] = (f16)W2[c][n]
// 4 rows/block (vs 8) -> 576 blocks = ~2.25/CU for latency hiding.
__global__ __launch_bounds__(256) void prep_all(
    const float* __restrict__ queries, const float* __restrict__ keys,
    const float* __restrict__ W1, const float* __restrict__ b1,
    const float* __restrict__ W2,
    float* __restrict__ qh, float* __restrict__ kh,
    unsigned short* __restrict__ W2T) {
    int i = blockIdx.x;
    int t = threadIdx.x;
    if (i >= 512) {  // ---- W2 transpose ----
        __shared__ float tile[32][33];
        int bi = i - 512;
        int tx = t & 31, ty = t >> 5;
        int tc = (bi & 7) * 32, tn = (bi >> 3) * 32;
#pragma unroll
        for (int r = 0; r < 4; ++r)
            tile[ty + r * 8][tx] = W2[(tc + ty + r * 8) * HD + tn + tx];
        __syncthreads();
#pragma unroll
        for (int r = 0; r < 4; ++r)
            W2T[(tn + ty + r * 8) * HD + tc + tx] = f2h(tile[tx][ty + r * 8]);
        return;
    }
    // ---- qh / kh ----
    bool isQ = i < 256;
    int r0 = (i & 255) * 4;
    const float* X = isQ ? queries : keys;
    const float* W = W1 + (isQ ? DIM * HD : 0);
    float* O = isQ ? qh : kh;
    __shared__ float xs[4][DIM];
#pragma unroll
    for (int r = 0; r < 4; ++r) xs[r][t] = X[(r0 + r) * DIM + t];
    __syncthreads();
    float acc[4] = {0.f, 0.f, 0.f, 0.f};
#pragma unroll 8
    for (int d = 0; d < DIM; ++d) {
        float w = W[d * HD + t];  // coalesced across t; 8 loads in flight
#pragma unroll
        for (int r = 0; r < 4; ++r) acc[r] = fmaf(xs[r][d], w, acc[r]);
    }
    float bias = isQ ? b1[t] : 0.f;
#pragma unroll
    for (int r = 0; r < 4; ++r) O[(r0 + r) * HD + t] = acc[r] + bias;
}

// One block per (b, q-pair): MFMA score rows for q0,q0+1 over 8 k-chunks of 32,
// double-buffered LDS A with 4-deep prefetch pipelined into the MFMA loop,
// W2T slice pinned in 128 VGPRs/wave; masked softmax + shared-load PV for 2 rows.
__global__ __launch_bounds__(256, 2) void mlp_attn(
    const float* __restrict__ qh, const float* __restrict__ kh,
    const unsigned short* __restrict__ W2T,
    const float* __restrict__ b2, const float* __restrict__ W3,
    const float* __restrict__ keys,
    const int* __restrict__ qlens, const int* __restrict__ klens,
    float* __restrict__ out) {
    int orig = blockIdx.x;
    // XCD-chunked swizzle: 512 blocks = 8 XCDs x 64; each XCD sees one batch b
    int bid = ((orig & 7) << 6) | (orig >> 3);
    int b = bid >> 7;
    int q0 = (bid & 127) << 1;
    int t = threadIdx.x;
    int qlen = qlens[b];
    float* orow = out + (b * TQ + q0) * DIM;   // row q0; row q0+1 at +DIM
    if (q0 >= qlen) { orow[t] = 0.f; orow[DIM + t] = 0.f; return; }  // uniform
    bool v1 = (q0 + 1) < qlen;
    int klen = klens[b];
    int nch = (klen + 31) >> 5;   // 4..8 valid 32-wide k chunks

    __shared__ uint4 Afrag[2][8][4][64];  // [buf][k-step][m-tile][lane], 2x32KB
    __shared__ float srow[2][TK];         // score partials -> probs (2 q rows)
    __shared__ float red[16];

    int w = t >> 6, lane = t & 63;
    int col = lane & 15, quad = lane >> 4;

    // ---- this wave's W2T slice: 32 x uint4 = 128 VGPR ----
    int nb = w << 6;
    uint4 bfr[4][8];
    float b2v[4], w3v[4];
#pragma unroll
    for (int nt = 0; nt < 4; ++nt) {
        int n = nb + (nt << 4) + col;
        const uint4* r = (const uint4*)(W2T + n * HD) + quad;  // quad -> k-octet
#pragma unroll
        for (int s = 0; s < 8; ++s) bfr[nt][s] = r[s * 4];
        b2v[nt] = b2[n];
        w3v[nt] = W3[n];
    }

    // staging role: wave w stages m-tile w: q = w>>1, rows (w&1)*16 + col,
    // h-octet = quad*8 + s*32. Wave writes Afrag[d][s][w][0..63] = 1KB
    // contiguous -> bank-conflict-free (old map was 4-way conflicted).
    int qsel = w >> 1;
    int rsub = ((w & 1) << 4) | col;
    const float* qrow = qh + (b * TQ + q0 + qsel) * HD + (quad << 3);  // b1 folded
    const float* kbase = kh + b * TK * HD + (quad << 3);

    // ---- prologue: stage chunk 0 into buffer 0 ----
    {
        const float* krow = kbase + rsub * HD;
        uint4* as = &Afrag[0][0][w][lane];
#pragma unroll 2
        for (int s = 0; s < 8; ++s) {
            const float4 k0 = *(const float4*)(krow + s * 32);
            const float4 k1 = *(const float4*)(krow + s * 32 + 4);
            const float4 qa = *(const float4*)(qrow + s * 32);
            const float4 qb = *(const float4*)(qrow + s * 32 + 4);
            uint4 wv;
            wv.x = pk2h(fmaxf(k0.x + qa.x, 0.f), fmaxf(k0.y + qa.y, 0.f));
            wv.y = pk2h(fmaxf(k0.z + qa.z, 0.f), fmaxf(k0.w + qa.w, 0.f));
            wv.z = pk2h(fmaxf(k1.x + qb.x, 0.f), fmaxf(k1.y + qb.y, 0.f));
            wv.w = pk2h(fmaxf(k1.z + qb.z, 0.f), fmaxf(k1.w + qb.w, 0.f));
            as[s * 256] = wv;
        }
    }
    srow[0][t] = 0.f;
    srow[1][t] = 0.f;

    // Pin the B slice: opaque-define so it can't be sunk/rematerialized.
#pragma unroll
    for (int nt = 0; nt < 4; ++nt)
#pragma unroll
        for (int s = 0; s < 8; ++s) {
            KEEP(bfr[nt][s].x); KEEP(bfr[nt][s].y);
            KEEP(bfr[nt][s].z); KEEP(bfr[nt][s].w);
        }

    __syncthreads();      // buffer 0 staged, srow zeroed

    for (int c = 0; c < nch; ++c) {
        int cur = c & 1;
        bool stg = (c + 1 < nch);
        const float* krow = kbase + (((c + 1) << 5) + rsub) * HD;
        uint4* as = &Afrag[cur ^ 1][0][w][lane];
        // 4-deep k prefetch: steps 0..3 in flight before MFMAs start.
        float4 Rk0[4], Rk1[4];
        if (stg) {
#pragma unroll
            for (int p = 0; p < 4; ++p) {
                Rk0[p] = *(const float4*)(krow + p * 32);
                Rk1[p] = *(const float4*)(krow + p * 32 + 4);
            }
        }

        // mt-half passes (hf = q within pair) keep acc at 32 VGPRs so the
        // 32 prefetch regs fit without spilling.
#pragma unroll
        for (int hf = 0; hf < 2; ++hf) {
            f32x4 acc[2][4] = {};
#pragma unroll
            for (int s = 0; s < 8; ++s) {
#pragma unroll
                for (int m2 = 0; m2 < 2; ++m2) {
                    U4H8 au;
                    au.u = Afrag[cur][s][(hf << 1) | m2][lane];
#pragma unroll
                    for (int nt = 0; nt < 4; ++nt) {
                        U4H8 bu;
                        bu.u = bfr[nt][s];
                        acc[m2][nt] = __builtin_amdgcn_mfma_f32_16x16x32_f16(
                            au.v, bu.v, acc[m2][nt], 0, 0, 0);
                    }
                }
                // staging interleave (half 0 only): write step s (its loads
                // were issued 4 steps = ~320cy ago -> vmcnt satisfied, no
                // stall in front of the next ds_read), then issue step s+4.
                if (hf == 0 && stg) {
                    int rp = s & 3;   // static after full unroll
                    const float4 qa = *(const float4*)(qrow + s * 32);
                    const float4 qb = *(const float4*)(qrow + s * 32 + 4);
                    uint4 wv;
                    wv.x = pk2h(fmaxf(Rk0[rp].x + qa.x, 0.f), fmaxf(Rk0[rp].y + qa.y, 0.f));
                    wv.y = pk2h(fmaxf(Rk0[rp].z + qa.z, 0.f), fmaxf(Rk0[rp].w + qa.w, 0.f));
                    wv.z = pk2h(fmaxf(Rk1[rp].x + qb.x, 0.f), fmaxf(Rk1[rp].y + qb.y, 0.f));
                    wv.w = pk2h(fmaxf(Rk1[rp].z + qb.z, 0.f), fmaxf(Rk1[rp].w + qb.w, 0.f));
                    as[s * 256] = wv;
                    if (s < 4) {
                        Rk0[rp] = *(const float4*)(krow + (s + 4) * 32);
                        Rk1[rp] = *(const float4*)(krow + (s + 4) * 32 + 4);
                    }
                }
            }
            // epilogue: relu(+b2) * W3, reduce over n, accumulate scores
#pragma unroll
            for (int m2 = 0; m2 < 2; ++m2) {
                float part[4];
#pragma unroll
                for (int r = 0; r < 4; ++r) {
                    float pa = 0.f;
#pragma unroll
                    for (int nt = 0; nt < 4; ++nt)
                        pa = fmaf(fmaxf(acc[m2][nt][r] + b2v[nt], 0.f), w3v[nt], pa);
                    part[r] = pa;
                }
#pragma unroll
                for (int off = 1; off < 16; off <<= 1)
#pragma unroll
                    for (int r = 0; r < 4; ++r)
                        part[r] += __shfl_xor(part[r], off, 64);
                if (col == 0)
#pragma unroll
                    for (int r = 0; r < 4; ++r)
                        atomicAdd(&srow[hf][(c << 5) | (m2 << 4) | (quad << 2) | r],
                                  part[r]);
            }
        }
        __syncthreads();  // stage(c+1) visible, atomics done, buf cur free
    }

    // ---- masked softmax over both score rows ----
    float s0 = (t < klen) ? srow[0][t] : -3.4e38f;
    float s1 = (t < klen) ? srow[1][t] : -3.4e38f;
    float m0 = s0, m1 = s1;
#pragma unroll
    for (int off = 1; off < 64; off <<= 1) {
        m0 = fmaxf(m0, __shfl_xor(m0, off, 64));
        m1 = fmaxf(m1, __shfl_xor(m1, off, 64));
    }
    if (lane == 0) { red[w] = m0; red[8 + w] = m1; }
    __syncthreads();
    m0 = fmaxf(fmaxf(red[0], red[1]), fmaxf(red[2], red[3]));
    m1 = fmaxf(fmaxf(red[8], red[9]), fmaxf(red[10], red[11]));
    float e0 = (t < klen) ? __expf(s0 - m0) : 0.f;
    float e1 = (t < klen) ? __expf(s1 - m1) : 0.f;
    float u0 = e0, u1 = e1;
#pragma unroll
    for (int off = 1; off < 64; off <<= 1) {
        u0 += __shfl_xor(u0, off, 64);
        u1 += __shfl_xor(u1, off, 64);
    }
    if (lane == 0) { red[4 + w] = u0; red[12 + w] = u1; }
    __syncthreads();
    float d0 = red[4] + red[5] + red[6] + red[7];
    float d1 = red[12] + red[13] + red[14] + red[15];
    srow[0][t] = e0 / d0;   // probs q0
    srow[1][t] = e1 / d1;   // probs q0+1
    __syncthreads();

    // ---- PV: both rows share each keys load ----
    float a0 = 0.f, a1 = 0.f;
    const float* kp = keys + b * TK * DIM + t;  // coalesced: t = channel
#pragma unroll 8
    for (int k = 0; k < klen; ++k) {
        float v = kp[k * DIM];
        a0 = fmaf(srow[0][k], v, a0);
        a1 = fmaf(srow[1][k], v, a1);
    }
    orow[t] = a0;
    orow[DIM + t] = v1 ? a1 : 0.f;
}

extern "C" void kernel_launch(void* const* d_in, const int* in_sizes, int n_in,
                              void* d_out, int out_size, void* d_ws, size_t ws_size,
                              hipStream_t stream) {
    (void)in_sizes; (void)n_in; (void)out_size; (void)ws_size;
    const float* queries = (const float*)d_in[0];
    const float* keys    = (const float*)d_in[1];
    const int*   qlens   = (const int*)d_in[2];
    const int*   klens   = (const int*)d_in[3];
    const float* W1      = (const float*)d_in[4];
    const float* b1      = (const float*)d_in[5];
    const float* W2      = (const float*)d_in[6];
    const float* b2      = (const float*)d_in[7];
    const float* W3      = (const float*)d_in[8];
    float* out = (float*)d_out;

    float* qh = (float*)d_ws;                     // 4*256*256 f32 = 1 MB (b1 folded)
    float* kh = qh + BATCH * TQ * HD;             // 1 MB
    unsigned short* W2T = (unsigned short*)(kh + BATCH * TK * HD);  // 128 KB

    prep_all<<<576, 256, 0, stream>>>(queries, keys, W1, b1, W2, qh, kh, W2T);
    mlp_attn<<<BATCH * TQ / 2, 256, 0, stream>>>(
        qh, kh, W2T, b2, W3, keys, qlens, klens, out);
}

// Round 2
// 145.956 us; speedup vs baseline: 1.0227x; 1.0227x over previous
//
#include <hip/hip_runtime.h>
#include <cstdint>

#define BATCH 4
#define TQ 256
#define TK 256
#define DIM 256
#define HD 256

typedef _Float16 f16x8 __attribute__((ext_vector_type(8)));
typedef float f32x4 __attribute__((ext_vector_type(4)));

union U4H8 { uint4 u; f16x8 v; };

// Opaque def+use: forces the value to be materialized in a VGPR here and
// prevents the compiler from sinking/rematerializing the producing load.
#define KEEP(x) asm volatile("" : "+v"(x))

__device__ __forceinline__ unsigned short f2h(float f) {
    _Float16 h = (_Float16)f;
    unsigned short u;
    __builtin_memcpy(&u, &h, 2);
    return u;
}

__device__ __forceinline__ uint32_t pk2h(float a, float b) {
    auto r = __builtin_amdgcn_cvt_pkrtz(a, b);
    uint32_t w;
    __builtin_memcpy(&w, &r, 4);
    return w;
}

// Fused prep: blocks 0..511  -> qh = queries@W1[256:]+b1, kh = keys@W1[:256]
//             blocks 512..575 -> W2T[n][c] = (f16)W2[c][n]
__global__ __launch_bounds__(256) void prep_all(
    const float* __restrict__ queries, const float* __restrict__ keys,
    const float* __restrict__ W1, const float* __restrict__ b1,
    const float* __restrict__ W2,
    float* __restrict__ qh, float* __restrict__ kh,
    unsigned short* __restrict__ W2T) {
    int i = blockIdx.x;
    int t = threadIdx.x;
    if (i >= 512) {  // ---- W2 transpose ----
        __shared__ float tile[32][33];
        int bi = i - 512;
        int tx = t & 31, ty = t >> 5;
        int tc = (bi & 7) * 32, tn = (bi >> 3) * 32;
#pragma unroll
        for (int r = 0; r < 4; ++r)
            tile[ty + r * 8][tx] = W2[(tc + ty + r * 8) * HD + tn + tx];
        __syncthreads();
#pragma unroll
        for (int r = 0; r < 4; ++r)
            W2T[(tn + ty + r * 8) * HD + tc + tx] = f2h(tile[tx][ty + r * 8]);
        return;
    }
    // ---- qh / kh ----
    bool isQ = i < 256;
    int r0 = (i & 255) * 4;
    const float* X = isQ ? queries : keys;
    const float* W = W1 + (isQ ? DIM * HD : 0);
    float* O = isQ ? qh : kh;
    __shared__ float xs[4][DIM];
#pragma unroll
    for (int r = 0; r < 4; ++r) xs[r][t] = X[(r0 + r) * DIM + t];
    __syncthreads();
    float acc[4] = {0.f, 0.f, 0.f, 0.f};
#pragma unroll 8
    for (int d = 0; d < DIM; ++d) {
        float w = W[d * HD + t];  // coalesced across t; 8 loads in flight
#pragma unroll
        for (int r = 0; r < 4; ++r) acc[r] = fmaf(xs[r][d], w, acc[r]);
    }
    float bias = isQ ? b1[t] : 0.f;
#pragma unroll
    for (int r = 0; r < 4; ++r) O[(r0 + r) * HD + t] = acc[r] + bias;
}

// One block per (b, q-pair): MFMA score rows for q0,q0+1 over 8 k-chunks of 32,
// double-buffered LDS A, W2T slice pinned in 128 VGPRs/wave.
// Epilogue is ATOMIC-FREE: per-wave n-slice partials go to wave-private LDS
// rows via plain ds_write_b128; softmax phase sums the 4 wave partials.
__global__ __launch_bounds__(256, 2) void mlp_attn(
    const float* __restrict__ qh, const float* __restrict__ kh,
    const unsigned short* __restrict__ W2T,
    const float* __restrict__ b2, const float* __restrict__ W3,
    const float* __restrict__ keys,
    const int* __restrict__ qlens, const int* __restrict__ klens,
    float* __restrict__ out) {
    int orig = blockIdx.x;
    // XCD-chunked swizzle: 512 blocks = 8 XCDs x 64; each XCD sees one batch b
    int bid = ((orig & 7) << 6) | (orig >> 3);
    int b = bid >> 7;
    int q0 = (bid & 127) << 1;
    int t = threadIdx.x;
    int qlen = qlens[b];
    float* orow = out + (b * TQ + q0) * DIM;   // row q0; row q0+1 at +DIM
    if (q0 >= qlen) { orow[t] = 0.f; orow[DIM + t] = 0.f; return; }  // uniform
    bool v1 = (q0 + 1) < qlen;
    int klen = klens[b];
    int nch = (klen + 31) >> 5;   // 4..8 valid 32-wide k chunks

    __shared__ uint4 Afrag[2][8][4][64];  // [buf][k-step][m-tile][lane], 2x32KB
    __shared__ float sprt[4][2][TK];      // per-wave score partials, 8KB
    __shared__ float srow[2][TK];         // probs (2 q rows)
    __shared__ float red[16];

    int w = t >> 6, lane = t & 63;
    int col = lane & 15, quad = lane >> 4;

    // ---- this wave's W2T slice: 32 x uint4 = 128 VGPR ----
    int nb = w << 6;
    uint4 bfr[4][8];
    float b2v[4], w3v[4];
#pragma unroll
    for (int nt = 0; nt < 4; ++nt) {
        int n = nb + (nt << 4) + col;
        const uint4* r = (const uint4*)(W2T + n * HD) + quad;  // quad -> k-octet
#pragma unroll
        for (int s = 0; s < 8; ++s) bfr[nt][s] = r[s * 4];
        b2v[nt] = b2[n];
        w3v[nt] = W3[n];
    }

    // staging role: wave w stages m-tile w: q = w>>1, rows (w&1)*16 + col,
    // h-octet = quad*8 + s*32. Wave writes Afrag[d][s][w][0..63] = 1KB
    // contiguous -> bank-conflict-free.
    int rsub = ((w & 1) << 4) | col;
    const float* qrow = qh + (b * TQ + q0 + (w >> 1)) * HD + (quad << 3);  // b1 folded
    const float* kbase = kh + b * TK * HD + (quad << 3);

    // Separated straight-line stage of chunk c into buffer d (full unroll:
    // the scheduler hoists the 16 k + 16 q loads to keep many in flight).
    auto stage = [&](int c, int d) {
        const float* krow = kbase + ((c << 5) + rsub) * HD;
        uint4* as = &Afrag[d][0][w][lane];
#pragma unroll
        for (int s = 0; s < 8; ++s) {
            const float4 k0 = *(const float4*)(krow + s * 32);
            const float4 k1 = *(const float4*)(krow + s * 32 + 4);
            const float4 qa = *(const float4*)(qrow + s * 32);
            const float4 qb = *(const float4*)(qrow + s * 32 + 4);
            uint4 wv;
            wv.x = pk2h(fmaxf(k0.x + qa.x, 0.f), fmaxf(k0.y + qa.y, 0.f));
            wv.y = pk2h(fmaxf(k0.z + qa.z, 0.f), fmaxf(k0.w + qa.w, 0.f));
            wv.z = pk2h(fmaxf(k1.x + qb.x, 0.f), fmaxf(k1.y + qb.y, 0.f));
            wv.w = pk2h(fmaxf(k1.z + qb.z, 0.f), fmaxf(k1.w + qb.w, 0.f));
            as[s * 256] = wv;
        }
    };

    stage(0, 0);

    // Pin the B slice: opaque-define so it can't be sunk/rematerialized.
#pragma unroll
    for (int nt = 0; nt < 4; ++nt)
#pragma unroll
        for (int s = 0; s < 8; ++s) {
            KEEP(bfr[nt][s].x); KEEP(bfr[nt][s].y);
            KEEP(bfr[nt][s].z); KEEP(bfr[nt][s].w);
        }

    __syncthreads();      // buffer 0 staged

    for (int c = 0; c < nch; ++c) {
        int cur = c & 1;
        if (c + 1 < nch) stage(c + 1, cur ^ 1);  // loads overlap MFMAs below

#pragma unroll
        for (int hf = 0; hf < 2; ++hf) {
            f32x4 acc[2][4] = {};
#pragma unroll
            for (int s = 0; s < 8; ++s) {
#pragma unroll
                for (int m2 = 0; m2 < 2; ++m2) {
                    U4H8 au;
                    au.u = Afrag[cur][s][(hf << 1) | m2][lane];
#pragma unroll
                    for (int nt = 0; nt < 4; ++nt) {
                        U4H8 bu;
                        bu.u = bfr[nt][s];
                        acc[m2][nt] = __builtin_amdgcn_mfma_f32_16x16x32_f16(
                            au.v, bu.v, acc[m2][nt], 0, 0, 0);
                    }
                }
            }
            // epilogue: relu(+b2) * W3, reduce over n (16 cols), then one
            // plain ds_write_b128 per active lane into the wave-private row.
#pragma unroll
            for (int m2 = 0; m2 < 2; ++m2) {
                float part[4];
#pragma unroll
                for (int r = 0; r < 4; ++r) {
                    float pa = 0.f;
#pragma unroll
                    for (int nt = 0; nt < 4; ++nt)
                        pa = fmaf(fmaxf(acc[m2][nt][r] + b2v[nt], 0.f), w3v[nt], pa);
                    part[r] = pa;
                }
#pragma unroll
                for (int off = 1; off < 16; off <<= 1)
#pragma unroll
                    for (int r = 0; r < 4; ++r)
                        part[r] += __shfl_xor(part[r], off, 64);
                if (col == 0) {
                    float4 p4 = make_float4(part[0], part[1], part[2], part[3]);
                    *(float4*)&sprt[w][hf][(c << 5) | (m2 << 4) | (quad << 2)] = p4;
                }
            }
        }
        __syncthreads();  // stage(c+1) + sprt writes visible, buf cur free
    }

    // ---- masked softmax over both score rows (sum the 4 wave partials) ----
    float s0 = -3.4e38f, s1 = -3.4e38f;
    if (t < klen) {
        s0 = (sprt[0][0][t] + sprt[1][0][t]) + (sprt[2][0][t] + sprt[3][0][t]);
        s1 = (sprt[0][1][t] + sprt[1][1][t]) + (sprt[2][1][t] + sprt[3][1][t]);
    }
    float m0 = s0, m1 = s1;
#pragma unroll
    for (int off = 1; off < 64; off <<= 1) {
        m0 = fmaxf(m0, __shfl_xor(m0, off, 64));
        m1 = fmaxf(m1, __shfl_xor(m1, off, 64));
    }
    if (lane == 0) { red[w] = m0; red[8 + w] = m1; }
    __syncthreads();
    m0 = fmaxf(fmaxf(red[0], red[1]), fmaxf(red[2], red[3]));
    m1 = fmaxf(fmaxf(red[8], red[9]), fmaxf(red[10], red[11]));
    float e0 = (t < klen) ? __expf(s0 - m0) : 0.f;
    float e1 = (t < klen) ? __expf(s1 - m1) : 0.f;
    float u0 = e0, u1 = e1;
#pragma unroll
    for (int off = 1; off < 64; off <<= 1) {
        u0 += __shfl_xor(u0, off, 64);
        u1 += __shfl_xor(u1, off, 64);
    }
    if (lane == 0) { red[4 + w] = u0; red[12 + w] = u1; }
    __syncthreads();
    float d0 = red[4] + red[5] + red[6] + red[7];
    float d1 = red[12] + red[13] + red[14] + red[15];
    srow[0][t] = e0 / d0;   // probs q0
    srow[1][t] = e1 / d1;   // probs q0+1
    __syncthreads();

    // ---- PV: both rows share each keys load ----
    float a0 = 0.f, a1 = 0.f;
    const float* kp = keys + b * TK * DIM + t;  // coalesced: t = channel
#pragma unroll 8
    for (int k = 0; k < klen; ++k) {
        float v = kp[k * DIM];
        a0 = fmaf(srow[0][k], v, a0);
        a1 = fmaf(srow[1][k], v, a1);
    }
    orow[t] = a0;
    orow[DIM + t] = v1 ? a1 : 0.f;
}

extern "C" void kernel_launch(void* const* d_in, const int* in_sizes, int n_in,
                              void* d_out, int out_size, void* d_ws, size_t ws_size,
                              hipStream_t stream) {
    (void)in_sizes; (void)n_in; (void)out_size; (void)ws_size;
    const float* queries = (const float*)d_in[0];
    const float* keys    = (const float*)d_in[1];
    const int*   qlens   = (const int*)d_in[2];
    const int*   klens   = (const int*)d_in[3];
    const float* W1      = (const float*)d_in[4];
    const float* b1      = (const float*)d_in[5];
    const float* W2      = (const float*)d_in[6];
    const float* b2      = (const float*)d_in[7];
    const float* W3      = (const float*)d_in[8];
    float* out = (float*)d_out;

    float* qh = (float*)d_ws;                     // 4*256*256 f32 = 1 MB (b1 folded)
    float* kh = qh + BATCH * TQ * HD;             // 1 MB
    unsigned short* W2T = (unsigned short*)(kh + BATCH * TK * HD);  // 128 KB

    prep_all<<<576, 256, 0, stream>>>(queries, keys, W1, b1, W2, qh, kh, W2T);
    mlp_attn<<<BATCH * TQ / 2, 256, 0, stream>>>(
        qh, kh, W2T, b2, W3, keys, qlens, klens, out);
}